// Round 10
// baseline (1848.414 us; speedup 1.0000x reference)
//
#include <hip/hip_runtime.h>

// MoE forward, MI355X. fp32 router/dispatch (exact top-k), bf16 MFMA grouped
// GEMMs (9 groups = 8 experts + shared), fp32-atomic scatter-combine.
// R9: push residency+bytes together. 256x128 tile, 8 waves, SINGLE-buffered
// 50KB LDS -> 3 blocks/CU = 24 waves/CU (vs R8's 16) AND 25% fewer staged
// bytes/flop. Same m97-family loop (stage->sync->compute->sync), same
// verified swizzle + XCD remap. __launch_bounds__(512,6) pins 3 blocks/CU.

#define NTOK 8192
#define DDIM 1024
#define HDIM 1408
#define CAP  2560
#define NROWS (NTOK + 8*CAP)   // 28672 GEMM rows: [0,8192) shared, then 8*2560 expert slots
#define YN   8388608           // NTOK*DDIM

typedef __bf16 bf16x8 __attribute__((ext_vector_type(8)));
typedef float  f32x4  __attribute__((ext_vector_type(4)));

typedef __attribute__((address_space(1))) void gvoid_t;
typedef __attribute__((address_space(3))) void svoid_t;

static __device__ __forceinline__ void load_lds16(const void* g, void* l) {
  // 16B per lane, LDS dest = wave-uniform base + lane*16 (linear)
  __builtin_amdgcn_global_load_lds((gvoid_t*)g, (svoid_t*)l, 16, 0, 0);
}

// ---------------- zero y + aux + accumulators ----------------
__global__ __launch_bounds__(256) void zero_kernel(float* __restrict__ y,
                                                   float* __restrict__ psum,
                                                   int* __restrict__ fcnt) {
  size_t idx = (size_t)blockIdx.x * 256 + threadIdx.x;
  float4 z = make_float4(0.f, 0.f, 0.f, 0.f);
  float4* p = (float4*)y;
#pragma unroll
  for (int j = 0; j < 4; ++j) p[idx + (size_t)j * 524288] = z;
  if (idx == 0) {
    y[YN] = 0.f;
    for (int e = 0; e < 8; ++e) { psum[e] = 0.f; fcnt[e] = 0; }
  }
}

// ---------------- fp32 -> bf16 (x) ----------------
__global__ __launch_bounds__(256) void convx_kernel(const float* __restrict__ in,
                                                    __bf16* __restrict__ out) {
  size_t i = ((size_t)blockIdx.x * 256 + threadIdx.x) * 8;
  float4 a = *(const float4*)(in + i);
  float4 b = *(const float4*)(in + i + 4);
  bf16x8 o;
  o[0] = (__bf16)a.x; o[1] = (__bf16)a.y; o[2] = (__bf16)a.z; o[3] = (__bf16)a.w;
  o[4] = (__bf16)b.x; o[5] = (__bf16)b.y; o[6] = (__bf16)b.z; o[7] = (__bf16)b.w;
  *(bf16x8*)(out + i) = o;
}

// ---------------- transpose + convert weights: in[R][C] f32 -> out[C][R] bf16 ----------------
__global__ __launch_bounds__(256) void tconv_kernel(const float* __restrict__ in,
                                                    __bf16* __restrict__ out, int R, int C) {
  __shared__ float t[32][33];
  size_t mo = (size_t)blockIdx.z * R * C;
  const float* ip = in + mo;
  __bf16* op = out + mo;
  int c0 = blockIdx.x * 32, r0 = blockIdx.y * 32;
  int tx = threadIdx.x, ty = threadIdx.y;  // block (32,8)
#pragma unroll
  for (int k2 = 0; k2 < 4; ++k2)
    t[ty + k2 * 8][tx] = ip[(size_t)(r0 + ty + k2 * 8) * C + c0 + tx];
  __syncthreads();
#pragma unroll
  for (int k2 = 0; k2 < 4; ++k2)
    op[(size_t)(c0 + ty + k2 * 8) * R + r0 + tx] = (__bf16)t[tx][ty + k2 * 8];
}

// ---------------- router: fp32 logits, softmax, top-2, renorm, aux stats ----------------
__global__ __launch_bounds__(256) void router_kernel(
    const float* __restrict__ x, const float* __restrict__ rw,
    int2* __restrict__ e01, float2* __restrict__ p01,
    int* __restrict__ tok_row, float* __restrict__ scale_row,
    float* __restrict__ psum, int* __restrict__ fcnt) {
  __shared__ float rwl[8 * 1024];
  __shared__ float ps[8];
  __shared__ int fc[8];
  int tid = threadIdx.x;
  if (tid < 8) { ps[tid] = 0.f; fc[tid] = 0; }
  float4* rl4 = (float4*)rwl;
  const float4* rg4 = (const float4*)rw;
#pragma unroll
  for (int j = 0; j < 8; ++j) rl4[tid + 256 * j] = rg4[tid + 256 * j];
  __syncthreads();
  int lane = tid & 63, wid = tid >> 6;
  for (int it = 0; it < 8; ++it) {
    int t = blockIdx.x * 32 + wid * 8 + it;
    const float4* xt = (const float4*)(x + (size_t)t * DDIM);
    float a[8];
#pragma unroll
    for (int e = 0; e < 8; ++e) a[e] = 0.f;
#pragma unroll
    for (int jj = 0; jj < 4; ++jj) {
      float4 v = xt[lane * 4 + jj];
#pragma unroll
      for (int e = 0; e < 8; ++e) {
        float4 w = rl4[e * 256 + lane * 4 + jj];
        a[e] += v.x * w.x + v.y * w.y + v.z * w.z + v.w * w.w;
      }
    }
#pragma unroll
    for (int off = 32; off >= 1; off >>= 1)
#pragma unroll
      for (int e = 0; e < 8; ++e) a[e] += __shfl_xor(a[e], off);
    if (lane == 0) {
      int am = 0; float m = a[0];
      for (int e = 1; e < 8; ++e) if (a[e] > m) { m = a[e]; am = e; }
      float s = 0.f, ex[8];
      for (int e = 0; e < 8; ++e) { ex[e] = expf(a[e] - m); s += ex[e]; }
      float inv = 1.f / s;
      int am2 = -1; float m2 = -3.4e38f;
      for (int e = 0; e < 8; ++e) if (e != am && a[e] > m2) { m2 = a[e]; am2 = e; }
      float p0 = ex[am] * inv, p1 = ex[am2] * inv;
      float rn = 1.f / (p0 + p1 + 1e-9f);
      e01[t] = make_int2(am, am2);
      p01[t] = make_float2(p0 * rn, p1 * rn);
      tok_row[t] = t;            // shared-group rows: identity gather, weight 1
      scale_row[t] = 1.f;
      atomicAdd(&fc[am], 1);
      for (int e = 0; e < 8; ++e) atomicAdd(&ps[e], ex[e] * inv);
    }
  }
  __syncthreads();
  if (tid < 8) { atomicAdd(&psum[tid], ps[tid]); atomicAdd(&fcnt[tid], fc[tid]); }
}

// ---------------- dispatch: stable rank within expert (token-major order), capacity drop ----------------
__global__ __launch_bounds__(256) void dispatch_kernel(
    const int2* __restrict__ e01, const float2* __restrict__ p01,
    int* __restrict__ tok_row, float* __restrict__ scale_row, int* __restrict__ counts) {
  __shared__ int lcnt[256][8];
  int tid = threadIdx.x;
  int my[8];
#pragma unroll
  for (int e = 0; e < 8; ++e) my[e] = 0;
  int base = tid * 64;  // 256 threads * 64 entries = 16384 = N*K, contiguous => stable
  for (int j = 0; j < 64; ++j) {
    int ent = base + j; int t = ent >> 1;
    int2 ee = e01[t];
    int ex = (ent & 1) ? ee.y : ee.x;
    my[ex]++;
  }
#pragma unroll
  for (int e = 0; e < 8; ++e) lcnt[tid][e] = my[e];
  __syncthreads();
  if (tid < 8) {
    int run = 0;
    for (int i = 0; i < 256; ++i) { int c = lcnt[i][tid]; lcnt[i][tid] = run; run += c; }
    counts[tid] = run < CAP ? run : CAP;
  }
  __syncthreads();
  int offs[8];
#pragma unroll
  for (int e = 0; e < 8; ++e) offs[e] = lcnt[tid][e];
  for (int j = 0; j < 64; ++j) {
    int ent = base + j; int t = ent >> 1; int k = ent & 1;
    int2 ee = e01[t];
    int ex = k ? ee.y : ee.x;
    float pr = k ? p01[t].y : p01[t].x;
    int pos = offs[ex]++;
    if (pos < CAP) {
      int row = NTOK + ex * CAP + pos;
      tok_row[row] = t;
      scale_row[row] = pr;
    }
  }
}

// ---------------- grouped GEMM, 256x128 tile, BK=64, 8 waves, single-buffer (m97 family) ----------------
// Per K-step/wave: 6 global_load_lds -> __syncthreads (compiler emits
// vmcnt(0)) -> 8 ds_read_b128 + 32 MFMA -> __syncthreads. Latency hiding via
// 3 resident blocks/CU (50KB LDS, launch_bounds(512,6) => 24 waves/CU).
// XOR chunk-swizzle: LDS[row][c] = global[row][c^(row&7)] (16B chunks),
// staged via swizzled per-lane SOURCE, read with matching XOR (0 conflicts).
// EPI==1: H = bf16(relu(acc)^2)   EPI==2: atomicAdd(y[tok][col], acc*scale)
template <int KD, int NDT, bool GATHER, int EPI>
__global__ __launch_bounds__(512, 6) void gemm_kernel(
    const __bf16* __restrict__ A, const __bf16* __restrict__ B,
    __bf16* __restrict__ Hout, float* __restrict__ Yout,
    const int* __restrict__ counts, const int* __restrict__ tok_row,
    const float* __restrict__ scale_row) {
  constexpr int BM = 256, BN = 128;
  constexpr int NCT = NDT / BN;    // 11 (GEMM1) or 8 (GEMM2)
  constexpr int SH = NTOK / BM;    // 32 shared row-tiles
  constexpr int ET = CAP / BM;     // 10 expert row-tiles (worst case)
  // XCD bijective remap + 4-rt chunks (nwg%8==0, nwg%(4*NCT)==0 hold)
  int nwg = gridDim.x;
  int lin = (blockIdx.x & 7) * (nwg >> 3) + (blockIdx.x >> 3);
  int rem = lin % (4 * NCT);
  int rt = (lin / (4 * NCT)) * 4 + (rem & 3);
  int ct = rem >> 2;

  int g, i0, rowbase;
  if (rt < SH) { g = 8; rowbase = 0; i0 = rt * BM; }
  else { int r = rt - SH; g = r / ET; i0 = (r % ET) * BM; rowbase = NTOK + g * CAP; }
  int cnt = (g == 8) ? NTOK : counts[g];
  if (i0 >= cnt) return;  // uniform early-exit

  __shared__ __align__(16) __bf16 As[BM * 64];   // 32 KB
  __shared__ __align__(16) __bf16 Bs[BN * 64];   // 16 KB
  __shared__ int   toksL[BM];
  __shared__ float sclL[BM];

  int tid = threadIdx.x, lane = tid & 63, wid = tid >> 6;

  if (tid < BM) {
    int i = i0 + tid; if (i > cnt - 1) i = cnt - 1;  // pad rows duplicate last valid
    toksL[tid] = tok_row[rowbase + i];
    if (EPI == 2) sclL[tid] = scale_row[rowbase + i];
  }
  __syncthreads();

  // staging pointers: 8 lanes cover one 128B k-row; 16B chunk swizzled by row&7
  int rsub = lane >> 3, csub = lane & 7;
  int csw = (csub ^ rsub) * 16;
  const char* aP[4];   // A: 8 waves x 4 instrs x 8 rows = 256 rows
  const char* bP[2];   // B: 8 waves x 2 instrs x 8 rows = 128 rows
  const char* Bg = (const char*)B + (size_t)g * NDT * KD * 2;
#pragma unroll
  for (int t = 0; t < 4; ++t) {
    int ia = wid * 32 + t * 8 + rsub;
    size_t arow = GATHER ? (size_t)toksL[ia] : (size_t)(rowbase + i0 + ia);
    aP[t] = (const char*)A + arow * (size_t)(KD * 2) + csw;
  }
#pragma unroll
  for (int t = 0; t < 2; ++t) {
    int ib = ct * BN + wid * 16 + t * 8 + rsub;
    bP[t] = Bg + (size_t)ib * (KD * 2) + csw;
  }

  f32x4 acc[4][4];
#pragma unroll
  for (int m2 = 0; m2 < 4; ++m2)
#pragma unroll
    for (int n2 = 0; n2 < 4; ++n2) acc[m2][n2] = f32x4{0.f, 0.f, 0.f, 0.f};

  int wr = wid >> 1, wc = wid & 1;   // wave tile 64x64 at (wr*64, wc*64)
  // hoisted LDS read offsets (element units); chunk' = chunk ^ (row&7), row&7 == lane&7
  int rA[4], rB[4], cS[2];
#pragma unroll
  for (int m2 = 0; m2 < 4; ++m2) rA[m2] = (wr * 64 + m2 * 16 + (lane & 15)) * 64;
#pragma unroll
  for (int n2 = 0; n2 < 4; ++n2) rB[n2] = (wc * 64 + n2 * 16 + (lane & 15)) * 64;
#pragma unroll
  for (int kk = 0; kk < 2; ++kk) cS[kk] = ((kk * 4 + (lane >> 4)) ^ (lane & 7)) * 8;

  // m97 structure: stage -> sync -> compute -> sync, single buffer.
  for (int k0 = 0; k0 < KD; k0 += 64) {
    size_t kb = (size_t)k0 * 2;
#pragma unroll
    for (int t = 0; t < 4; ++t)
      load_lds16(aP[t] + kb, &As[(wid * 32 + t * 8) * 64]);
#pragma unroll
    for (int t = 0; t < 2; ++t)
      load_lds16(bP[t] + kb, &Bs[(wid * 16 + t * 8) * 64]);
    __syncthreads();   // compiler inserts s_waitcnt vmcnt(0) before barrier
#pragma unroll
    for (int kk = 0; kk < 2; ++kk) {
      bf16x8 af[4], bfr[4];
#pragma unroll
      for (int m2 = 0; m2 < 4; ++m2) af[m2] = *(const bf16x8*)&As[rA[m2] + cS[kk]];
#pragma unroll
      for (int n2 = 0; n2 < 4; ++n2) bfr[n2] = *(const bf16x8*)&Bs[rB[n2] + cS[kk]];
#pragma unroll
      for (int m2 = 0; m2 < 4; ++m2)
#pragma unroll
        for (int n2 = 0; n2 < 4; ++n2)
          acc[m2][n2] = __builtin_amdgcn_mfma_f32_16x16x32_bf16(af[m2], bfr[n2], acc[m2][n2], 0, 0, 0);
    }
    __syncthreads();   // protect LDS reuse next iteration
  }

  // epilogue; C/D frag: col = lane&15, row = (lane>>4)*4 + reg  [verified m89/m91]
#pragma unroll
  for (int m2 = 0; m2 < 4; ++m2) {
    int rb = wr * 64 + m2 * 16 + ((lane >> 4) << 2);
#pragma unroll
    for (int n2 = 0; n2 < 4; ++n2) {
      int col = ct * BN + wc * 64 + n2 * 16 + (lane & 15);
#pragma unroll
      for (int r = 0; r < 4; ++r) {
        int grow = i0 + rb + r;
        if (grow < cnt) {
          float v = acc[m2][n2][r];
          if constexpr (EPI == 1) {
            v = fmaxf(v, 0.f);
            Hout[(size_t)(rowbase + grow) * NDT + col] = (__bf16)(v * v);
          } else {
            atomicAdd(&Yout[(size_t)toksL[rb + r] * NDT + col], v * sclL[rb + r]);
          }
        }
      }
    }
  }
}

// ---------------- aux loss ----------------
__global__ void aux_kernel(const float* __restrict__ psum, const int* __restrict__ fcnt,
                           float* __restrict__ out) {
  float s = 0.f;
  for (int e = 0; e < 8; ++e) s += ((float)fcnt[e] / 8192.f) * (psum[e] / 8192.f);
  *out = 0.08f * s;  // AUX_COEF * E = 0.01 * 8
}

extern "C" void kernel_launch(void* const* d_in, const int* in_sizes, int n_in,
                              void* d_out, int out_size, void* d_ws, size_t ws_size,
                              hipStream_t stream) {
  const float* x      = (const float*)d_in[0];
  const float* rw     = (const float*)d_in[1];
  const float* wfc    = (const float*)d_in[2];
  const float* wproj  = (const float*)d_in[3];
  const float* wsfc   = (const float*)d_in[4];
  const float* wsproj = (const float*)d_in[5];
  float* y = (float*)d_out;

  char* ws = (char*)d_ws;
  size_t off = 0;
  auto alloc = [&](size_t bytes) {
    void* p = ws + off;
    off += (bytes + 1023) & ~(size_t)1023;
    return p;
  };
  __bf16* xbf      = (__bf16*)alloc((size_t)NTOK * DDIM * 2);          // 16 MB
  __bf16* B1       = (__bf16*)alloc((size_t)9 * HDIM * DDIM * 2);      // 26 MB [9][1408][1024]
  __bf16* B2       = (__bf16*)alloc((size_t)9 * DDIM * HDIM * 2);      // 26 MB [9][1024][1408]
  __bf16* H        = (__bf16*)alloc((size_t)NROWS * HDIM * 2);         // 81 MB
  int*    tok_row  = (int*)alloc((size_t)NROWS * 4);
  float*  scale_row= (float*)alloc((size_t)NROWS * 4);
  int2*   e01      = (int2*)alloc((size_t)NTOK * 8);
  float2* p01      = (float2*)alloc((size_t)NTOK * 8);
  int*    counts   = (int*)alloc(1024);
  float*  psum     = (float*)alloc(1024);
  int*    fcnt     = (int*)alloc(1024);
  (void)ws_size; (void)out_size; (void)in_sizes; (void)n_in;

  zero_kernel<<<2048, 256, 0, stream>>>(y, psum, fcnt);
  convx_kernel<<<4096, 256, 0, stream>>>(x, xbf);
  dim3 tb(32, 8);
  tconv_kernel<<<dim3(44, 32, 8), tb, 0, stream>>>(wfc, B1, 1024, 1408);
  tconv_kernel<<<dim3(44, 32, 1), tb, 0, stream>>>(wsfc, B1 + (size_t)8 * HDIM * DDIM, 1024, 1408);
  tconv_kernel<<<dim3(32, 44, 8), tb, 0, stream>>>(wproj, B2, 1408, 1024);
  tconv_kernel<<<dim3(32, 44, 1), tb, 0, stream>>>(wsproj, B2 + (size_t)8 * DDIM * HDIM, 1408, 1024);
  router_kernel<<<256, 256, 0, stream>>>(x, rw, e01, p01, tok_row, scale_row, psum, fcnt);
  dispatch_kernel<<<1, 256, 0, stream>>>(e01, p01, tok_row, scale_row, counts);
  // GEMM1: H = relu(gather(x) @ B1)^2 ; 256x128 tiles: (32 + 8*10) rt * 11 ct = 1232
  gemm_kernel<1024, 1408, true, 1><<<1232, 512, 0, stream>>>(
      xbf, B1, H, nullptr, counts, tok_row, scale_row);
  // GEMM2: y[tok] += scale * (H @ B2) ; 256x128 tiles: 112 rt * 8 ct = 896
  gemm_kernel<1408, 1024, false, 2><<<896, 512, 0, stream>>>(
      H, B2, nullptr, y, counts, tok_row, scale_row);
  aux_kernel<<<1, 1, 0, stream>>>(psum, fcnt, y + YN);
}

// Round 11
// 319.438 us; speedup vs baseline: 5.7864x; 5.7864x over previous
//
#include <hip/hip_runtime.h>

// MoE forward, MI355X. fp32 router/dispatch (exact top-k), bf16 MFMA grouped
// GEMMs (9 groups = 8 experts + shared), fp32-atomic scatter-combine.
// R10: revert GEMMs to R8 exactly (128x128, 4 waves, single-buffer,
// launch_bounds(256,4) => 4 blocks/CU; VERIFIED 131us/GEMM). R9 lesson:
// per-SIMD VGPR pool = 512 wave-regs; launch_bounds(512,6) capped regs at
// 512/6=85 < 124 needed -> acc spilled to scratch (3.3GB traffic, 7x slower).
// (256,4) caps at 128 >= 124: this tile is at its register-bound occupancy
// max. New: convx fused into router (x read once; xbf written there).

#define NTOK 8192
#define DDIM 1024
#define HDIM 1408
#define CAP  2560
#define NROWS (NTOK + 8*CAP)   // 28672 GEMM rows: [0,8192) shared, then 8*2560 expert slots
#define YN   8388608           // NTOK*DDIM

typedef __bf16 bf16x8 __attribute__((ext_vector_type(8)));
typedef float  f32x4  __attribute__((ext_vector_type(4)));

typedef __attribute__((address_space(1))) void gvoid_t;
typedef __attribute__((address_space(3))) void svoid_t;

static __device__ __forceinline__ void load_lds16(const void* g, void* l) {
  // 16B per lane, LDS dest = wave-uniform base + lane*16 (linear)
  __builtin_amdgcn_global_load_lds((gvoid_t*)g, (svoid_t*)l, 16, 0, 0);
}

// ---------------- zero y + aux + accumulators ----------------
__global__ __launch_bounds__(256) void zero_kernel(float* __restrict__ y,
                                                   float* __restrict__ psum,
                                                   int* __restrict__ fcnt) {
  size_t idx = (size_t)blockIdx.x * 256 + threadIdx.x;
  float4 z = make_float4(0.f, 0.f, 0.f, 0.f);
  float4* p = (float4*)y;
#pragma unroll
  for (int j = 0; j < 4; ++j) p[idx + (size_t)j * 524288] = z;
  if (idx == 0) {
    y[YN] = 0.f;
    for (int e = 0; e < 8; ++e) { psum[e] = 0.f; fcnt[e] = 0; }
  }
}

// ---------------- transpose + convert weights: in[R][C] f32 -> out[C][R] bf16 ----------------
__global__ __launch_bounds__(256) void tconv_kernel(const float* __restrict__ in,
                                                    __bf16* __restrict__ out, int R, int C) {
  __shared__ float t[32][33];
  size_t mo = (size_t)blockIdx.z * R * C;
  const float* ip = in + mo;
  __bf16* op = out + mo;
  int c0 = blockIdx.x * 32, r0 = blockIdx.y * 32;
  int tx = threadIdx.x, ty = threadIdx.y;  // block (32,8)
#pragma unroll
  for (int k2 = 0; k2 < 4; ++k2)
    t[ty + k2 * 8][tx] = ip[(size_t)(r0 + ty + k2 * 8) * C + c0 + tx];
  __syncthreads();
#pragma unroll
  for (int k2 = 0; k2 < 4; ++k2)
    op[(size_t)(c0 + ty + k2 * 8) * R + r0 + tx] = (__bf16)t[tx][ty + k2 * 8];
}

// ------- router (+ fused x->bf16 convert): fp32 logits, softmax, top-2, renorm, aux -------
__global__ __launch_bounds__(256) void router_kernel(
    const float* __restrict__ x, const float* __restrict__ rw,
    __bf16* __restrict__ xbf,
    int2* __restrict__ e01, float2* __restrict__ p01,
    int* __restrict__ tok_row, float* __restrict__ scale_row,
    float* __restrict__ psum, int* __restrict__ fcnt) {
  __shared__ float rwl[8 * 1024];
  __shared__ float ps[8];
  __shared__ int fc[8];
  int tid = threadIdx.x;
  if (tid < 8) { ps[tid] = 0.f; fc[tid] = 0; }
  float4* rl4 = (float4*)rwl;
  const float4* rg4 = (const float4*)rw;
#pragma unroll
  for (int j = 0; j < 8; ++j) rl4[tid + 256 * j] = rg4[tid + 256 * j];
  __syncthreads();
  int lane = tid & 63, wid = tid >> 6;
  for (int it = 0; it < 8; ++it) {
    int t = blockIdx.x * 32 + wid * 8 + it;
    const float4* xt = (const float4*)(x + (size_t)t * DDIM);
    float a[8];
#pragma unroll
    for (int e = 0; e < 8; ++e) a[e] = 0.f;
    float4 v[4];
#pragma unroll
    for (int jj = 0; jj < 4; ++jj) {
      v[jj] = xt[lane * 4 + jj];
#pragma unroll
      for (int e = 0; e < 8; ++e) {
        float4 w = rl4[e * 256 + lane * 4 + jj];
        a[e] += v[jj].x * w.x + v[jj].y * w.y + v[jj].z * w.z + v[jj].w * w.w;
      }
    }
    // fused convert: this lane owns x[t][lane*16 .. lane*16+15]
    {
      bf16x8 o0, o1;
#pragma unroll
      for (int jj = 0; jj < 2; ++jj) {
        o0[jj * 4 + 0] = (__bf16)v[jj].x; o0[jj * 4 + 1] = (__bf16)v[jj].y;
        o0[jj * 4 + 2] = (__bf16)v[jj].z; o0[jj * 4 + 3] = (__bf16)v[jj].w;
        o1[jj * 4 + 0] = (__bf16)v[jj + 2].x; o1[jj * 4 + 1] = (__bf16)v[jj + 2].y;
        o1[jj * 4 + 2] = (__bf16)v[jj + 2].z; o1[jj * 4 + 3] = (__bf16)v[jj + 2].w;
      }
      __bf16* xo = xbf + (size_t)t * DDIM + lane * 16;
      *(bf16x8*)xo = o0;
      *(bf16x8*)(xo + 8) = o1;
    }
#pragma unroll
    for (int off = 32; off >= 1; off >>= 1)
#pragma unroll
      for (int e = 0; e < 8; ++e) a[e] += __shfl_xor(a[e], off);
    if (lane == 0) {
      int am = 0; float m = a[0];
      for (int e = 1; e < 8; ++e) if (a[e] > m) { m = a[e]; am = e; }
      float s = 0.f, ex[8];
      for (int e = 0; e < 8; ++e) { ex[e] = expf(a[e] - m); s += ex[e]; }
      float inv = 1.f / s;
      int am2 = -1; float m2 = -3.4e38f;
      for (int e = 0; e < 8; ++e) if (e != am && a[e] > m2) { m2 = a[e]; am2 = e; }
      float p0 = ex[am] * inv, p1 = ex[am2] * inv;
      float rn = 1.f / (p0 + p1 + 1e-9f);
      e01[t] = make_int2(am, am2);
      p01[t] = make_float2(p0 * rn, p1 * rn);
      tok_row[t] = t;            // shared-group rows: identity gather, weight 1
      scale_row[t] = 1.f;
      atomicAdd(&fc[am], 1);
      for (int e = 0; e < 8; ++e) atomicAdd(&ps[e], ex[e] * inv);
    }
  }
  __syncthreads();
  if (tid < 8) { atomicAdd(&psum[tid], ps[tid]); atomicAdd(&fcnt[tid], fc[tid]); }
}

// ---------------- dispatch: stable rank within expert (token-major order), capacity drop ----------------
__global__ __launch_bounds__(256) void dispatch_kernel(
    const int2* __restrict__ e01, const float2* __restrict__ p01,
    int* __restrict__ tok_row, float* __restrict__ scale_row, int* __restrict__ counts) {
  __shared__ int lcnt[256][8];
  int tid = threadIdx.x;
  int my[8];
#pragma unroll
  for (int e = 0; e < 8; ++e) my[e] = 0;
  int base = tid * 64;  // 256 threads * 64 entries = 16384 = N*K, contiguous => stable
  for (int j = 0; j < 64; ++j) {
    int ent = base + j; int t = ent >> 1;
    int2 ee = e01[t];
    int ex = (ent & 1) ? ee.y : ee.x;
    my[ex]++;
  }
#pragma unroll
  for (int e = 0; e < 8; ++e) lcnt[tid][e] = my[e];
  __syncthreads();
  if (tid < 8) {
    int run = 0;
    for (int i = 0; i < 256; ++i) { int c = lcnt[i][tid]; lcnt[i][tid] = run; run += c; }
    counts[tid] = run < CAP ? run : CAP;
  }
  __syncthreads();
  int offs[8];
#pragma unroll
  for (int e = 0; e < 8; ++e) offs[e] = lcnt[tid][e];
  for (int j = 0; j < 64; ++j) {
    int ent = base + j; int t = ent >> 1; int k = ent & 1;
    int2 ee = e01[t];
    int ex = k ? ee.y : ee.x;
    float pr = k ? p01[t].y : p01[t].x;
    int pos = offs[ex]++;
    if (pos < CAP) {
      int row = NTOK + ex * CAP + pos;
      tok_row[row] = t;
      scale_row[row] = pr;
    }
  }
}

// ---------------- grouped GEMM, 128x128 tile, BK=64, 4 waves, single-buffer (m97 structure) ----------------
// R8-verified. Per K-step: 8 global_load_lds/wave -> __syncthreads (compiler
// emits vmcnt(0)) -> 16 ds_read_b128 + 32 MFMA -> __syncthreads. Latency
// hiding via 4 resident blocks/CU (33KB LDS, launch_bounds(256,4): VGPR cap
// 512/4 = 128 >= ~124 used -- do NOT raise waves/EU, acc spills: R9).
// XOR chunk-swizzle: LDS[row][c] = global[row][c^(row&7)] (16B chunks),
// staged via swizzled per-lane SOURCE, read with matching XOR (0 conflicts).
// EPI==1: H = bf16(relu(acc)^2)   EPI==2: atomicAdd(y[tok][col], acc*scale)
template <int KD, int NDT, bool GATHER, int EPI>
__global__ __launch_bounds__(256, 4) void gemm_kernel(
    const __bf16* __restrict__ A, const __bf16* __restrict__ B,
    __bf16* __restrict__ Hout, float* __restrict__ Yout,
    const int* __restrict__ counts, const int* __restrict__ tok_row,
    const float* __restrict__ scale_row) {
  constexpr int NCT = NDT / 128;
  constexpr int SH = NTOK / 128;   // 64 shared row-tiles
  constexpr int ET = CAP / 128;    // 20 expert row-tiles (worst case)
  // XCD bijective remap + 4-rt chunks (nwg%8==0, nwg%(4*NCT)==0 hold)
  int nwg = gridDim.x;
  int lin = (blockIdx.x & 7) * (nwg >> 3) + (blockIdx.x >> 3);
  int rem = lin % (4 * NCT);
  int rt = (lin / (4 * NCT)) * 4 + (rem & 3);
  int ct = rem >> 2;

  int g, i0, rowbase;
  if (rt < SH) { g = 8; rowbase = 0; i0 = rt << 7; }
  else { int r = rt - SH; g = r / ET; i0 = (r % ET) << 7; rowbase = NTOK + g * CAP; }
  int cnt = (g == 8) ? NTOK : counts[g];
  if (i0 >= cnt) return;  // uniform early-exit

  __shared__ __align__(16) __bf16 As[128 * 64];   // 16 KB
  __shared__ __align__(16) __bf16 Bs[128 * 64];   // 16 KB
  __shared__ int   toksL[128];
  __shared__ float sclL[128];

  int tid = threadIdx.x, lane = tid & 63, wid = tid >> 6;

  if (tid < 128) {
    int i = i0 + tid; if (i > cnt - 1) i = cnt - 1;  // pad rows duplicate last valid
    toksL[tid] = tok_row[rowbase + i];
    if (EPI == 2) sclL[tid] = scale_row[rowbase + i];
  }
  __syncthreads();

  // staging pointers: 8 lanes cover one 128B k-row; 16B chunk swizzled by row&7
  int rsub = lane >> 3, csub = lane & 7;
  int csw = (csub ^ rsub) * 16;
  const char* aP[4];
  const char* bP[4];
  const char* Bg = (const char*)B + (size_t)g * NDT * KD * 2;
#pragma unroll
  for (int t = 0; t < 4; ++t) {
    int ia = wid * 32 + t * 8 + rsub;
    size_t arow = GATHER ? (size_t)toksL[ia] : (size_t)(rowbase + i0 + ia);
    aP[t] = (const char*)A + arow * (size_t)(KD * 2) + csw;
    int ib = ct * 128 + wid * 32 + t * 8 + rsub;
    bP[t] = Bg + (size_t)ib * (KD * 2) + csw;
  }

  f32x4 acc[4][4];
#pragma unroll
  for (int m2 = 0; m2 < 4; ++m2)
#pragma unroll
    for (int n2 = 0; n2 < 4; ++n2) acc[m2][n2] = f32x4{0.f, 0.f, 0.f, 0.f};

  int wr = wid >> 1, wc = wid & 1;   // wave tile 64x64 at (wr*64, wc*64)
  // hoisted LDS read offsets (element units); chunk' = chunk ^ (row&7), row&7 == lane&7
  int rA[4], rB[4], cS[2];
#pragma unroll
  for (int m2 = 0; m2 < 4; ++m2) rA[m2] = (wr * 64 + m2 * 16 + (lane & 15)) * 64;
#pragma unroll
  for (int n2 = 0; n2 < 4; ++n2) rB[n2] = (wc * 64 + n2 * 16 + (lane & 15)) * 64;
#pragma unroll
  for (int kk = 0; kk < 2; ++kk) cS[kk] = ((kk * 4 + (lane >> 4)) ^ (lane & 7)) * 8;

  // m97 structure: stage -> sync -> compute -> sync, single buffer.
  for (int k0 = 0; k0 < KD; k0 += 64) {
    size_t kb = (size_t)k0 * 2;
#pragma unroll
    for (int t = 0; t < 4; ++t) {
      load_lds16(aP[t] + kb, &As[(wid * 32 + t * 8) * 64]);
      load_lds16(bP[t] + kb, &Bs[(wid * 32 + t * 8) * 64]);
    }
    __syncthreads();   // compiler inserts s_waitcnt vmcnt(0) before barrier
#pragma unroll
    for (int kk = 0; kk < 2; ++kk) {
      bf16x8 af[4], bfr[4];
#pragma unroll
      for (int m2 = 0; m2 < 4; ++m2) af[m2] = *(const bf16x8*)&As[rA[m2] + cS[kk]];
#pragma unroll
      for (int n2 = 0; n2 < 4; ++n2) bfr[n2] = *(const bf16x8*)&Bs[rB[n2] + cS[kk]];
#pragma unroll
      for (int m2 = 0; m2 < 4; ++m2)
#pragma unroll
        for (int n2 = 0; n2 < 4; ++n2)
          acc[m2][n2] = __builtin_amdgcn_mfma_f32_16x16x32_bf16(af[m2], bfr[n2], acc[m2][n2], 0, 0, 0);
    }
    __syncthreads();   // protect LDS reuse next iteration
  }

  // epilogue; C/D frag: col = lane&15, row = (lane>>4)*4 + reg  [verified m89/m91]
#pragma unroll
  for (int m2 = 0; m2 < 4; ++m2) {
    int rb = wr * 64 + m2 * 16 + ((lane >> 4) << 2);
#pragma unroll
    for (int n2 = 0; n2 < 4; ++n2) {
      int col = ct * 128 + wc * 64 + n2 * 16 + (lane & 15);
#pragma unroll
      for (int r = 0; r < 4; ++r) {
        int grow = i0 + rb + r;
        if (grow < cnt) {
          float v = acc[m2][n2][r];
          if constexpr (EPI == 1) {
            v = fmaxf(v, 0.f);
            Hout[(size_t)(rowbase + grow) * NDT + col] = (__bf16)(v * v);
          } else {
            atomicAdd(&Yout[(size_t)toksL[rb + r] * NDT + col], v * sclL[rb + r]);
          }
        }
      }
    }
  }
}

// ---------------- aux loss ----------------
__global__ void aux_kernel(const float* __restrict__ psum, const int* __restrict__ fcnt,
                           float* __restrict__ out) {
  float s = 0.f;
  for (int e = 0; e < 8; ++e) s += ((float)fcnt[e] / 8192.f) * (psum[e] / 8192.f);
  *out = 0.08f * s;  // AUX_COEF * E = 0.01 * 8
}

extern "C" void kernel_launch(void* const* d_in, const int* in_sizes, int n_in,
                              void* d_out, int out_size, void* d_ws, size_t ws_size,
                              hipStream_t stream) {
  const float* x      = (const float*)d_in[0];
  const float* rw     = (const float*)d_in[1];
  const float* wfc    = (const float*)d_in[2];
  const float* wproj  = (const float*)d_in[3];
  const float* wsfc   = (const float*)d_in[4];
  const float* wsproj = (const float*)d_in[5];
  float* y = (float*)d_out;

  char* ws = (char*)d_ws;
  size_t off = 0;
  auto alloc = [&](size_t bytes) {
    void* p = ws + off;
    off += (bytes + 1023) & ~(size_t)1023;
    return p;
  };
  __bf16* xbf      = (__bf16*)alloc((size_t)NTOK * DDIM * 2);          // 16 MB
  __bf16* B1       = (__bf16*)alloc((size_t)9 * HDIM * DDIM * 2);      // 26 MB [9][1408][1024]
  __bf16* B2       = (__bf16*)alloc((size_t)9 * DDIM * HDIM * 2);      // 26 MB [9][1024][1408]
  __bf16* H        = (__bf16*)alloc((size_t)NROWS * HDIM * 2);         // 81 MB
  int*    tok_row  = (int*)alloc((size_t)NROWS * 4);
  float*  scale_row= (float*)alloc((size_t)NROWS * 4);
  int2*   e01      = (int2*)alloc((size_t)NTOK * 8);
  float2* p01      = (float2*)alloc((size_t)NTOK * 8);
  int*    counts   = (int*)alloc(1024);
  float*  psum     = (float*)alloc(1024);
  int*    fcnt     = (int*)alloc(1024);
  (void)ws_size; (void)out_size; (void)in_sizes; (void)n_in;

  zero_kernel<<<2048, 256, 0, stream>>>(y, psum, fcnt);
  dim3 tb(32, 8);
  tconv_kernel<<<dim3(44, 32, 8), tb, 0, stream>>>(wfc, B1, 1024, 1408);
  tconv_kernel<<<dim3(44, 32, 1), tb, 0, stream>>>(wsfc, B1 + (size_t)8 * HDIM * DDIM, 1024, 1408);
  tconv_kernel<<<dim3(32, 44, 8), tb, 0, stream>>>(wproj, B2, 1408, 1024);
  tconv_kernel<<<dim3(32, 44, 1), tb, 0, stream>>>(wsproj, B2 + (size_t)8 * DDIM * HDIM, 1408, 1024);
  router_kernel<<<256, 256, 0, stream>>>(x, rw, xbf, e01, p01, tok_row, scale_row, psum, fcnt);
  dispatch_kernel<<<1, 256, 0, stream>>>(e01, p01, tok_row, scale_row, counts);
  // GEMM1: H = relu(gather(x) @ B1)^2 ; 128x128 tiles: (64 + 8*20) rt * 11 ct = 2464
  gemm_kernel<1024, 1408, true, 1><<<2464, 256, 0, stream>>>(
      xbf, B1, H, nullptr, counts, tok_row, scale_row);
  // GEMM2: y[tok] += scale * (H @ B2) ; 128x128 tiles: 224 rt * 8 ct = 1792
  gemm_kernel<1408, 1024, false, 2><<<1792, 256, 0, stream>>>(
      H, B2, nullptr, y, counts, tok_row, scale_row);
  aux_kernel<<<1, 1, 0, stream>>>(psum, fcnt, y + YN);
}